// Round 2
// baseline (68.796 us; speedup 1.0000x reference)
//
#include <hip/hip_runtime.h>

#define POOL 7
#define CCH 256
#define GCH 16            // channels per block
#define HH 100
#define WW 100
#define HW (HH * WW)
#define MAXSPAN 28        // worst-case ROI sub-tile span is <=26; +2 margin
#define NTAP 14           // POOL * NSAMP samples per axis

static constexpr float SCALE = 0.125f;

// One block per (roi, 16-channel group). Stage the ROI's feature sub-tile
// (<=MAXSPAN^2 per channel) for 16 channels into LDS with W-coalesced row
// loads directly from NCHW, then compute all 7x7 bins from LDS.
__global__ __launch_bounds__(256) void roi_align_tiled(
    const float* __restrict__ x, const float* __restrict__ rois,
    float* __restrict__ out)
{
    __shared__ float tile[GCH * MAXSPAN * MAXSPAN];      // ~50 KB
    __shared__ int   s_lo[2][NTAP], s_hi[2][NTAP];       // [0]=x axis, [1]=y axis
    __shared__ float s_w1[2][NTAP], s_w2[2][NTAP];
    __shared__ int   s_b[4];                             // xmin, ymin, TW, TH

    const int bid = blockIdx.x;
    const int r   = bid >> 4;            // 16 channel-groups per ROI
    const int c0  = (bid & 15) * GCH;
    const int t   = threadIdx.x;

    const float r0  = rois[r * 5 + 0];
    const float fx1 = rois[r * 5 + 1];
    const float fy1 = rois[r * 5 + 2];
    const float fx2 = rois[r * 5 + 3];
    const float fy2 = rois[r * 5 + 4];
    const int   n   = (int)r0;
    const float sx0 = fx1 * SCALE - 0.5f;
    const float sy0 = fy1 * SCALE - 0.5f;
    const float bw  = (fx2 * SCALE - 0.5f - sx0) * (1.0f / POOL);
    const float bh  = (fy2 * SCALE - 0.5f - sy0) * (1.0f / POOL);

    // ---- tap tables: 14 x-samples + 14 y-samples ----
    if (t < 2 * NTAP) {
        const int   axis = t / NTAP;     // 0 = x, 1 = y
        const int   k    = t % NTAP;
        const int   p    = k >> 1;       // bin index along axis
        const int   si   = k & 1;        // sample index within bin
        const float g    = (float)p + ((float)si + 0.5f) * 0.5f;
        const float cc   = axis ? (sy0 + g * bh) : (sx0 + g * bw);
        const float L    = axis ? (float)HH : (float)WW;
        const int   Li   = axis ? HH : WW;
        const bool  valid = (cc > -1.0f) && (cc < L);
        float cl = fminf(fmaxf(cc, 0.0f), L - 1.0f);
        int   lo = (int)floorf(cl);
        if (lo > Li - 1) lo = Li - 1;
        int   hi = lo + 1;
        if (hi > Li - 1) hi = Li - 1;
        const float fr = cl - (float)lo;
        s_lo[axis][k] = lo;
        s_hi[axis][k] = hi;
        s_w1[axis][k] = valid ? 1.0f - fr : 0.0f;
        s_w2[axis][k] = valid ? fr : 0.0f;
    }
    __syncthreads();

    if (t == 0) {
        int xmin = s_lo[0][0], xmax = s_hi[0][0];
        int ymin = s_lo[1][0], ymax = s_hi[1][0];
        #pragma unroll
        for (int k = 1; k < NTAP; ++k) {
            xmin = min(xmin, s_lo[0][k]); xmax = max(xmax, s_hi[0][k]);
            ymin = min(ymin, s_lo[1][k]); ymax = max(ymax, s_hi[1][k]);
        }
        int TW = xmax - xmin + 1; if (TW > MAXSPAN) TW = MAXSPAN;  // defensive
        int TH = ymax - ymin + 1; if (TH > MAXSPAN) TH = MAXSPAN;
        s_b[0] = xmin; s_b[1] = ymin; s_b[2] = TW; s_b[3] = TH;
    }
    __syncthreads();

    const int xmin = s_b[0], ymin = s_b[1], TW = s_b[2], TH = s_b[3];
    const int chstride = TH * TW;

    // ---- stage: W-coalesced row loads from NCHW into compact LDS tile ----
    {
        const float* xb = x + ((size_t)n * CCH + c0) * HW
                            + (size_t)ymin * WW + xmin;
        const int tx = t & 31;           // column within row (TW <= 28 <= 32)
        const int ty = t >> 5;           // 8 row-streams
        if (tx < TW) {
            for (int p = ty; p < GCH * TH; p += 8) {
                const int ch = p & (GCH - 1);
                const int yy = p >> 4;
                tile[ch * chstride + yy * TW + tx] =
                    xb[(size_t)ch * HW + yy * WW + tx];
            }
        }
    }
    __syncthreads();

    // ---- compute: thread = (channel, 3-4 bins), all reads from LDS ----
    const int   ch = t >> 4;             // 0..15
    const int   b0 = t & 15;
    const float* tc = tile + ch * chstride;
    float* op = out + ((size_t)r * CCH + c0 + ch) * (POOL * POOL);

    #pragma unroll
    for (int i = 0; i < 4; ++i) {
        const int b = b0 + i * 16;
        if (b < POOL * POOL) {
            const int py = b / POOL;
            const int px = b - py * POOL;
            float acc = 0.0f;
            #pragma unroll
            for (int sy = 0; sy < 2; ++sy) {
                const int   ky  = py * 2 + sy;
                const int   yl  = s_lo[1][ky] - ymin;
                const int   yh  = s_hi[1][ky] - ymin;
                const float wy1 = s_w1[1][ky];
                const float wy2 = s_w2[1][ky];
                #pragma unroll
                for (int sx = 0; sx < 2; ++sx) {
                    const int   kx  = px * 2 + sx;
                    const int   xl  = s_lo[0][kx] - xmin;
                    const int   xh  = s_hi[0][kx] - xmin;
                    const float wx1 = s_w1[0][kx];
                    const float wx2 = s_w2[0][kx];
                    acc += wy1 * (wx1 * tc[yl * TW + xl] + wx2 * tc[yl * TW + xh])
                         + wy2 * (wx1 * tc[yh * TW + xl] + wx2 * tc[yh * TW + xh]);
                }
            }
            op[b] = acc * 0.25f;
        }
    }
}

extern "C" void kernel_launch(void* const* d_in, const int* in_sizes, int n_in,
                              void* d_out, int out_size, void* d_ws, size_t ws_size,
                              hipStream_t stream) {
    const float* x    = (const float*)d_in[0];
    const float* rois = (const float*)d_in[1];
    float*       out  = (float*)d_out;

    const int R   = in_sizes[1] / 5;
    const int nwg = R * (CCH / GCH);     // one block per (roi, channel-group)

    roi_align_tiled<<<nwg, 256, 0, stream>>>(x, rois, out);
}